// Round 1
// 141.798 us; speedup vs baseline: 1.2595x; 1.2595x over previous
//
#include <hip/hip_runtime.h>
#include <math.h>

// VectorQuantizer — bit-exact emulation of the numpy fp32 reference (proven R2-R11):
//   d[n,k] = fl32( fl32(x2[n]+c2[k]) - fl32(2 * fl32(exact_fp64_dot)) ), first argmin.
//
// R13: move the filter GEMM to the matrix cores (MfmaUtil was 0.0 at 126us;
// fp32-VALU floor is ~27us so the old structure was capped). Filter uses
// mfma_f32_16x16x32_f16 with an f16 hi/lo split of BOTH x and codebook
// (3 products: xh*ch + xl*ch + xh*cl; lo parts scaled by 2^12 to avoid f16
// subnormals, recombined in fp32). Filter error <= ~4e-5 << THR=1.2e-4, so
// the candidate set provably contains the exact argmin:
//   |ek_fast[k] - (dk_exact[k] - x2)| <= E,  THR >= 2E  =>
//   every exact-argmin (incl. ties) passes ek <= fastmin + THR.
// Single-candidate shortcut: if exactly ONE code passes for a row it IS the
// exact argmin (any j: ek[j] > ek[k]+2E => dk[j] > dk[k]) -> no fp64 needed.
// Only near-tie rows (~2-4%) hit the unchanged bit-exact fp64 resolver.

#define N_CODES   512
#define CODE_DIM  64
#define CH_STRIDE 4096                      // floats between channels
#define B_STRIDE  (CODE_DIM * CH_STRIDE)    // floats between batches
#define THR       1.2e-4f                   // >= 2*(dk-formula rounding + f16-split filter err)

typedef _Float16 f16x8 __attribute__((ext_vector_type(8)));
typedef float    f32x4 __attribute__((ext_vector_type(4)));

__device__ __forceinline__ unsigned short f16_bits(_Float16 h) {
    union { _Float16 f; unsigned short u; } cv; cv.f = h; return cv.u;
}

__device__ __forceinline__ uint4 pack8u16(const unsigned short* s) {
    uint4 v;
    v.x = (unsigned)s[0] | ((unsigned)s[1] << 16);
    v.y = (unsigned)s[2] | ((unsigned)s[3] << 16);
    v.z = (unsigned)s[4] | ((unsigned)s[5] << 16);
    v.w = (unsigned)s[6] | ((unsigned)s[7] << 16);
    return v;
}

// ---------------- setup: c2 (numpy pairwise) + f16 hi/lo B-frag tables ------
__device__ __forceinline__ float np_pairwise_sum64(const float* a) {
    float r[8];
#pragma unroll
    for (int j = 0; j < 8; ++j) r[j] = a[j];
#pragma unroll
    for (int i = 8; i < 64; i += 8) {
#pragma unroll
        for (int j = 0; j < 8; ++j) r[j] = __fadd_rn(r[j], a[i + j]);
    }
    return __fadd_rn(__fadd_rn(__fadd_rn(r[0], r[1]), __fadd_rn(r[2], r[3])),
                     __fadd_rn(__fadd_rn(r[4], r[5]), __fadd_rn(r[6], r[7])));
}

// B-frag tables in exact MFMA B-operand order (16x16x32: n=lane&15,
// k=(lane>>4)*8+j): element index ((T*2+kk)*64 + lane)*8 + j  maps to
// cb[T*16 + (lane&15)][kk*32 + (lane>>4)*8 + j].
__global__ void vq_setup_kernel(const float* __restrict__ cb, float* __restrict__ c2,
                                unsigned short* __restrict__ bh,
                                unsigned short* __restrict__ bl, int buildT) {
    const int t = blockIdx.x * blockDim.x + threadIdx.x;   // 8 blocks x 512 = 4096
    if (buildT) {
        const int l    = t & 63;
        const int kkT  = t >> 6;                           // T*2+kk, 0..63
        const int code = (kkT >> 1) * 16 + (l & 15);
        const int d0   = (kkT & 1) * 32 + ((l >> 4) << 3);
        const float* crow = cb + code * CODE_DIM + d0;
        unsigned short hs[8], ls[8];
#pragma unroll
        for (int j = 0; j < 8; ++j) {
            const float c  = crow[j];
            const _Float16 h = (_Float16)c;                 // RNE
            const float lf = __fsub_rn(c, (float)h) * 4096.0f;  // exact (Sterbenz + pow2)
            hs[j] = f16_bits(h);
            ls[j] = f16_bits((_Float16)lf);                 // scaled lo: stays f16-normal
        }
        const uint4 hv = pack8u16(hs), lv = pack8u16(ls);
        *(uint4*)(bh + (size_t)t * 8) = hv;
        *(uint4*)(bl + (size_t)t * 8) = lv;
    }
    if (t < N_CODES) {
        const float* row = cb + t * CODE_DIM;
        float sq[CODE_DIM];
#pragma unroll
        for (int j = 0; j < CODE_DIM; ++j) sq[j] = __fmul_rn(row[j], row[j]);
        c2[t] = np_pairwise_sum64(sq);
    }
}

// Rare-path exact resolver (bit-identical R2 arithmetic; x re-read from global
// so the hot path needs no fp32 x in LDS). __noinline__: no register arrays,
// caller's ek[] stays in VGPRs.
__device__ __noinline__ void resolve_cell(const float* __restrict__ cb,
                                          const float* __restrict__ c2g,
                                          const float* __restrict__ src,
                                          unsigned long long* s_res,
                                          int row, int k) {
    // numpy-exact x2 (R5-proven rolling 8-acc pairwise order)
    float r[8];
#pragma unroll
    for (int j = 0; j < 8; ++j) {
        const float x = src[(size_t)j * CH_STRIDE + row];
        r[j] = __fmul_rn(x, x);
    }
#pragma unroll
    for (int i = 8; i < 64; i += 8) {
#pragma unroll
        for (int j = 0; j < 8; ++j) {
            const float x = src[(size_t)(i + j) * CH_STRIDE + row];
            r[j] = __fadd_rn(r[j], __fmul_rn(x, x));
        }
    }
    const float x2 = __fadd_rn(__fadd_rn(__fadd_rn(r[0], r[1]), __fadd_rn(r[2], r[3])),
                               __fadd_rn(__fadd_rn(r[4], r[5]), __fadd_rn(r[6], r[7])));
    const float* crow = cb + (size_t)k * CODE_DIM;
    double b0 = 0.0, b1 = 0.0, b2 = 0.0, b3 = 0.0;
#pragma unroll
    for (int c = 0; c < CODE_DIM; c += 4) {
        b0 = fma((double)crow[c + 0], (double)src[(size_t)(c + 0) * CH_STRIDE + row], b0);
        b1 = fma((double)crow[c + 1], (double)src[(size_t)(c + 1) * CH_STRIDE + row], b1);
        b2 = fma((double)crow[c + 2], (double)src[(size_t)(c + 2) * CH_STRIDE + row], b2);
        b3 = fma((double)crow[c + 3], (double)src[(size_t)(c + 3) * CH_STRIDE + row], b3);
    }
    const double dot64 = (b0 + b1) + (b2 + b3);
    const float  ein   = (float)dot64;
    const float  tmp   = __fadd_rn(x2, c2g[k]);
    const float  dk    = __fsub_rn(tmp, __fmul_rn(2.0f, ein));
    const unsigned u     = __float_as_uint(dk);
    const unsigned key32 = (u & 0x80000000u) ? ~u : (u | 0x80000000u);
    atomicMin(&s_res[row], ((unsigned long long)key32 << 32) | (unsigned)k);
}

// ---------------- main: MFMA filter + exact resolve -------------------------
// Block = one (b,h) group: 64 rows x 512 codes, 512 threads (8 waves).
// Wave wid: all 64 rows (4 M-tiles) x codes [wid*64, wid*64+64) (4 N-tiles).
__global__ __launch_bounds__(512, 2)
void vq_mfma_kernel(const float* __restrict__ in,
                    const float* __restrict__ cb,
                    const float* __restrict__ c2g,
                    const unsigned short* __restrict__ bhT,
                    const unsigned short* __restrict__ blT,
                    float* __restrict__ out) {
    __shared__ __align__(16) unsigned short aHi[4][2][512];  // A-frags [mt][kk][lane*8+j] 8KB
    __shared__ __align__(16) unsigned short aLo[4][2][512];  // 8KB
    __shared__ float s_wm[8][64];                            // per-wave row mins
    __shared__ float s_lim[64];                              // block min + THR
    __shared__ int   s_cnt[64];                              // candidates per row
    __shared__ int   s_win[64];                              // sole candidate (cnt==1)
    __shared__ unsigned long long s_res[64];                 // packed (dk-key, k)

    const int tid  = threadIdx.x;
    const int lane = tid & 63;
    const int wid  = tid >> 6;               // 0..7
    const int gw   = blockIdx.x;             // (b,h) group 0..1023
    const float* src = in + (size_t)(gw >> 6) * B_STRIDE + (size_t)(gw & 63) * 64;

    if (tid < 64) { s_cnt[tid] = 0; s_res[tid] = ~0ull; }

    // --- stage A-frags via registers (each input element read exactly once):
    //     wave wid -> (mt = wid>>1, kk = wid&1); lane l loads the 8 dims of
    //     its frag slot: row = mt*16+(l&15), k = (l>>4)*8+j (m92-verified map).
    {
        const int mt  = wid >> 1, kk = wid & 1;
        const int row = (mt << 4) + (lane & 15);
        const int d0  = (kk << 5) + ((lane >> 4) << 3);
        unsigned short hs[8], ls[8];
#pragma unroll
        for (int j = 0; j < 8; ++j) {
            const float x = src[(size_t)(d0 + j) * CH_STRIDE + row];
            const _Float16 h = (_Float16)x;
            const float lf = __fsub_rn(x, (float)h) * 4096.0f;
            hs[j] = f16_bits(h);
            ls[j] = f16_bits((_Float16)lf);
        }
        const uint4 hv = pack8u16(hs), lv = pack8u16(ls);
        *(uint4*)&aHi[mt][kk][lane * 8] = hv;
        *(uint4*)&aLo[mt][kk][lane * 8] = lv;
    }
    __syncthreads();

    // --- resident A-frags (16 x b128 LDS reads, lane-contiguous) ------------
    f16x8 Ah[4][2], Al[4][2];
#pragma unroll
    for (int mt = 0; mt < 4; ++mt)
#pragma unroll
        for (int kk = 0; kk < 2; ++kk) {
            Ah[mt][kk] = *(const f16x8*)&aHi[mt][kk][lane * 8];
            Al[mt][kk] = *(const f16x8*)&aLo[mt][kk][lane * 8];
        }

    const int nsub = lane & 15;
    float c2v[4];
#pragma unroll
    for (int t = 0; t < 4; ++t) c2v[t] = c2g[(wid << 6) + (t << 4) + nsub];

    // --- MFMA filter: ek = c2 - 2*(xh*ch + 2^-12*(xl'*ch + xh*cl')) ---------
    f32x4 ek[4][4];                  // [t][mt]
    float rm[4][4];                  // running row min [mt][reg]
#pragma unroll
    for (int mt = 0; mt < 4; ++mt)
#pragma unroll
        for (int r = 0; r < 4; ++r) rm[mt][r] = 1e30f;

#pragma unroll
    for (int t = 0; t < 4; ++t) {
        const int T2 = ((wid << 2) + t) << 1;   // global N-tile * 2
        const f16x8 Bh0 = *(const f16x8*)(bhT + ((size_t)(T2 + 0) * 64 + lane) * 8);
        const f16x8 Bh1 = *(const f16x8*)(bhT + ((size_t)(T2 + 1) * 64 + lane) * 8);
        const f16x8 Bl0 = *(const f16x8*)(blT + ((size_t)(T2 + 0) * 64 + lane) * 8);
        const f16x8 Bl1 = *(const f16x8*)(blT + ((size_t)(T2 + 1) * 64 + lane) * 8);
#pragma unroll
        for (int mt = 0; mt < 4; ++mt) {
            f32x4 a1 = {0.f, 0.f, 0.f, 0.f};
            f32x4 a2 = {0.f, 0.f, 0.f, 0.f};
            a1 = __builtin_amdgcn_mfma_f32_16x16x32_f16(Ah[mt][0], Bh0, a1, 0, 0, 0);
            a1 = __builtin_amdgcn_mfma_f32_16x16x32_f16(Ah[mt][1], Bh1, a1, 0, 0, 0);
            a2 = __builtin_amdgcn_mfma_f32_16x16x32_f16(Al[mt][0], Bh0, a2, 0, 0, 0);
            a2 = __builtin_amdgcn_mfma_f32_16x16x32_f16(Ah[mt][0], Bl0, a2, 0, 0, 0);
            a2 = __builtin_amdgcn_mfma_f32_16x16x32_f16(Al[mt][1], Bh1, a2, 0, 0, 0);
            a2 = __builtin_amdgcn_mfma_f32_16x16x32_f16(Ah[mt][1], Bl1, a2, 0, 0, 0);
            f32x4 e;
#pragma unroll
            for (int r = 0; r < 4; ++r) {
                const float d2 = __fmaf_rn(2.44140625e-4f, a2[r], a1[r]);  // +2^-12*lo
                const float v  = __fmaf_rn(-2.0f, d2, c2v[t]);
                e[r] = v;
                rm[mt][r] = fminf(rm[mt][r], v);
            }
            ek[t][mt] = e;
        }
    }

    // --- row min: reduce over the 16 lanes of each lane-group ---------------
#pragma unroll
    for (int s = 1; s < 16; s <<= 1)
#pragma unroll
        for (int mt = 0; mt < 4; ++mt)
#pragma unroll
            for (int r = 0; r < 4; ++r)
                rm[mt][r] = fminf(rm[mt][r], __shfl_xor(rm[mt][r], s, 64));

    if ((lane & 15) == 0) {
        const int g = lane >> 4;
#pragma unroll
        for (int mt = 0; mt < 4; ++mt)
#pragma unroll
            for (int r = 0; r < 4; ++r)
                s_wm[wid][(mt << 4) + (g << 2) + r] = rm[mt][r];
    }
    __syncthreads();
    if (tid < 64) {
        float m = s_wm[0][tid];
#pragma unroll
        for (int w = 1; w < 8; ++w) m = fminf(m, s_wm[w][tid]);
        s_lim[tid] = m + THR;
    }
    __syncthreads();

    // --- pass 1: count candidates per row (min always passes => cnt >= 1) ---
    const int rbase = (lane >> 4) << 2;
#pragma unroll
    for (int t = 0; t < 4; ++t)
#pragma unroll
        for (int mt = 0; mt < 4; ++mt)
#pragma unroll
            for (int r = 0; r < 4; ++r) {
                const int row = (mt << 4) + rbase + r;
                if (ek[t][mt][r] <= s_lim[row]) {
                    atomicAdd(&s_cnt[row], 1);
                    s_win[row] = (wid << 6) + (t << 4) + nsub;  // sole writer iff cnt==1
                }
            }
    __syncthreads();

    // --- pass 2: fp64 resolve only where >1 candidate (near-ties, ~2-4%) ----
#pragma unroll
    for (int t = 0; t < 4; ++t)
#pragma unroll
        for (int mt = 0; mt < 4; ++mt)
#pragma unroll
            for (int r = 0; r < 4; ++r) {
                const int row = (mt << 4) + rbase + r;
                if (ek[t][mt][r] <= s_lim[row] && s_cnt[row] > 1)
                    resolve_cell(cb, c2g, src, s_res, row, (wid << 6) + (t << 4) + nsub);
            }
    __syncthreads();

    // --- output: wave wid writes rows wid*8..+7 (coalesced 256B each) -------
    const size_t n0 = (size_t)gw * 64;
#pragma unroll
    for (int rr = 0; rr < 8; ++rr) {
        const int row = (wid << 3) + rr;
        const int idx = (s_cnt[row] == 1) ? s_win[row]
                                          : (int)(s_res[row] & 0xFFFFFFFFull);
        out[(n0 + row) * CODE_DIM + lane] = cb[(size_t)idx * CODE_DIM + lane];
    }
}

// ---------------- fallback (R9, proven 190us) if ws too small ---------------
__device__ __forceinline__ float exact_dk_fb(const float* __restrict__ cb,
                                             const float* __restrict__ c2,
                                             const float (&x)[CODE_DIM], float x2, int k) {
    const float* crow = cb + (size_t)k * CODE_DIM;
    double a0 = 0.0, a1 = 0.0, a2 = 0.0, a3 = 0.0;
#pragma unroll
    for (int j = 0; j < CODE_DIM; j += 4) {
        a0 = fma((double)crow[j + 0], (double)x[j + 0], a0);
        a1 = fma((double)crow[j + 1], (double)x[j + 1], a1);
        a2 = fma((double)crow[j + 2], (double)x[j + 2], a2);
        a3 = fma((double)crow[j + 3], (double)x[j + 3], a3);
    }
    const double dot = (a0 + a1) + (a2 + a3);
    const float  ein = (float)dot;
    return __fsub_rn(__fadd_rn(x2, c2[k]), __fmul_rn(2.0f, ein));
}

__global__ __launch_bounds__(512, 2)
void vq_fallback_kernel(const float* __restrict__ in, const float* __restrict__ cb,
                        const float* __restrict__ c2, float* __restrict__ out) {
    __shared__ float s_rb[8][64];
    __shared__ int   s_ri[8][64];
    const int tid = threadIdx.x, lane = tid & 63, wid = tid >> 6;
    const int gw = blockIdx.x, b = gw >> 6, h = gw & 63;
    const float* xin = in + (size_t)b * B_STRIDE + (size_t)h * 64 + lane;
    float x[CODE_DIM];
#pragma unroll
    for (int c = 0; c < CODE_DIM; ++c) x[c] = xin[(size_t)c * CH_STRIDE];
    float r[8];
#pragma unroll
    for (int j = 0; j < 8; ++j) r[j] = __fmul_rn(x[j], x[j]);
#pragma unroll
    for (int i = 8; i < 64; i += 8)
#pragma unroll
        for (int j = 0; j < 8; ++j) r[j] = __fadd_rn(r[j], __fmul_rn(x[i + j], x[i + j]));
    const float x2 = __fadd_rn(__fadd_rn(__fadd_rn(r[0], r[1]), __fadd_rn(r[2], r[3])),
                               __fadd_rn(__fadd_rn(r[4], r[5]), __fadd_rn(r[6], r[7])));
    const int k0 = __builtin_amdgcn_readfirstlane(wid) * 64;
    float ex_best = INFINITY; int bi = k0;
#pragma unroll 1
    for (int kk = 0; kk < 64; ++kk) {
        const float dk = exact_dk_fb(cb, c2, x, x2, k0 + kk);
        if (dk < ex_best) { ex_best = dk; bi = k0 + kk; }
    }
    s_rb[wid][lane] = ex_best; s_ri[wid][lane] = bi;
    __syncthreads();
    float fb2 = s_rb[0][lane]; int fi = s_ri[0][lane];
#pragma unroll
    for (int w = 1; w < 8; ++w) {
        if (s_rb[w][lane] < fb2) { fb2 = s_rb[w][lane]; fi = s_ri[w][lane]; }
    }
    const size_t n0 = (size_t)gw * 64;
#pragma unroll 1
    for (int rr = 0; rr < 8; ++rr) {
        const int row = wid * 8 + rr;
        const int idxr = __shfl(fi, row, 64);
        out[(n0 + row) * CODE_DIM + lane] = cb[(size_t)idxr * CODE_DIM + lane];
    }
}

extern "C" void kernel_launch(void* const* d_in, const int* in_sizes, int n_in,
                              void* d_out, int out_size, void* d_ws, size_t ws_size,
                              hipStream_t stream) {
    const float* in  = (const float*)d_in[0];   // (16,64,64,64) fp32
    const float* cb  = (const float*)d_in[1];   // (512,64) fp32
    float*       out = (float*)d_out;           // (16,64,64,64) fp32

    float* c2 = (float*)d_ws;                                    // 2 KB
    unsigned short* bh = (unsigned short*)((char*)d_ws + 2048);  // 64 KB f16-hi frags
    unsigned short* bl = (unsigned short*)((char*)d_ws + 2048 + 65536);  // 64 KB f16-lo
    const bool hasT = ws_size >= (size_t)(2048 + 2 * 65536);     // 133120 B (same as R12)

    vq_setup_kernel<<<dim3(8), dim3(512), 0, stream>>>(cb, c2, bh, bl, hasT ? 1 : 0);
    if (hasT) {
        // 1024 blocks = one (b,h) group each; 512 threads = 8 waves.
        vq_mfma_kernel<<<dim3(1024), dim3(512), 0, stream>>>(in, cb, c2, bh, bl, out);
    } else {
        vq_fallback_kernel<<<dim3(1024), dim3(512), 0, stream>>>(in, cb, c2, out);
    }
}